// Round 3
// baseline (26.963 us; speedup 1.0000x reference)
//
#include <hip/hip_runtime.h>
#include <cmath>

// Bokeh render, gather form:
// out[b,c,y,x] = sum_{dy,dx in [-4,4]} w * img[b,c,y-dy,x-dx] / sum w
// w = sigmoid(8*(r_src - dist)) / max(pi*r_src^2,1),
//     masked by max(|dy|,|dx|) <= floor(r_src)+1 and src in-bounds.
// r = |defocus| in [0,4) -> 9x9 window suffices.
//
// R2 lesson: at 4 px/thread the whole problem is only 2048 waves = 2
// waves/SIMD; the per-dy ds_read burst and its dependent VALU serialize
// (measured ~= sum of pipe times, not max). This version splits the 9 dy
// rows across two 256-thread groups in a 512-thread block (s=0: dy 0..4,
// s=1: dy 5..8) -> 4 waves/SIMD, partial sums combined through LDS.

#define HH 512
#define WW 512
#define NB 2
#define TILE 32
#define HALO 4
#define SROWS (TILE + 2 * HALO)   // 40
#define LW 44                     // LDS row stride (16B-aligned, conflict-free)
#define PSTRIDE 20                // partial-sum row stride (conflict-free octets)

__global__ __launch_bounds__(512, 4) void bokeh_gather(
    const float* __restrict__ img,
    const float* __restrict__ def,
    float* __restrict__ out)
{
  __shared__ __align__(16) float sG[SROWS][LW];
  __shared__ __align__(16) float sIv[SROWS][LW];
  __shared__ __align__(16) float sI0[SROWS][LW];
  __shared__ __align__(16) float sI1[SROWS][LW];
  __shared__ __align__(16) float sI2[SROWS][LW];
  __shared__ float sFd[9][12];   // exp(8*dist) per (dy,dx)
  __shared__ float sTh[9][12];   // exp(-8*(m-1)) per (dy,dx)
  __shared__ __align__(16) float pbuf[256][PSTRIDE];  // s=1 partial sums

  const int tid = threadIdx.x;
  const int s  = tid >> 8;       // dy-split group: 0 -> dy 0..4, 1 -> dy 5..8
  const int t  = tid & 255;
  const int tx = t & 7;          // 8 threads * 4 px = 32 cols
  const int ty = t >> 3;         // 32 rows
  const int bx = blockIdx.x * TILE;
  const int by = blockIdx.y * TILE;
  const int b  = blockIdx.z;

  if (tid < 81) {
    int dyi = tid / 9, dxi = tid - dyi * 9;
    int dyo = dyi - 4, dxo = dxi - 4;
    int ady = dyo < 0 ? -dyo : dyo;
    int adx = dxo < 0 ? -dxo : dxo;
    int m = ady > adx ? ady : adx;
    float d2 = (float)(dyo * dyo + dxo * dxo);
    sFd[dyi][dxi] = __expf(8.0f * sqrtf(d2));
    sTh[dyi][dxi] = __expf(-8.0f * (float)(m - 1));
  }

  const float* dpt = def + b * (HH * WW);
  const float* ipt = img + b * (3 * HH * WW);

  // Stage halo'd source tile. OOB sources -> zeros => weight exactly 0.
  for (int idx = tid; idx < SROWS * SROWS; idx += 512) {
    int ly = idx / SROWS;
    int lx = idx - ly * SROWS;
    int sy = by - HALO + ly;
    int sx = bx - HALO + lx;
    float G = 0.f, iv = 0.f, a0 = 0.f, a1 = 0.f, a2 = 0.f;
    if (sy >= 0 && sy < HH && sx >= 0 && sx < WW) {
      int o = sy * WW + sx;
      float r = fabsf(dpt[o]);
      G  = __expf(-8.0f * r);
      iv = __builtin_amdgcn_rcpf(fmaxf(3.14159265358979f * r * r, 1.0f));
      a0 = ipt[o];
      a1 = ipt[o + HH * WW];
      a2 = ipt[o + 2 * HH * WW];
    }
    sG[ly][lx]  = G;
    sIv[ly][lx] = iv;
    sI0[ly][lx] = a0;
    sI1[ly][lx] = a1;
    sI2[ly][lx] = a2;
  }
  __syncthreads();

  float wsum[4] = {0.f, 0.f, 0.f, 0.f};
  float ac0[4]  = {0.f, 0.f, 0.f, 0.f};
  float ac1[4]  = {0.f, 0.f, 0.f, 0.f};
  float ac2[4]  = {0.f, 0.f, 0.f, 0.f};

  const int col0 = 4 * tx;  // LDS col of source-window start (16B aligned)
  const int dy0 = s ? 5 : 0;
  const int dy1 = s ? 9 : 5;

  #pragma unroll 1
  for (int dy = dy0; dy < dy1; ++dy) {
    const int sr = ty + dy;
    float fdr[9], thv[9];
    #pragma unroll
    for (int x = 0; x < 9; ++x) { fdr[x] = sFd[dy][x]; thv[x] = sTh[dy][x]; }

    const float* rG = &sG[sr][col0];
    const float* rI = &sIv[sr][col0];
    const float* r0 = &sI0[sr][col0];
    const float* r1 = &sI1[sr][col0];
    const float* r2 = &sI2[sr][col0];
    float Gv[12], Iv[12], P0[12], P1[12], P2[12];
    #pragma unroll
    for (int q = 0; q < 3; ++q) {
      *(float4*)&Gv[4 * q] = *(const float4*)(rG + 4 * q);
      *(float4*)&Iv[4 * q] = *(const float4*)(rI + 4 * q);
      *(float4*)&P0[4 * q] = *(const float4*)(r0 + 4 * q);
      *(float4*)&P1[4 * q] = *(const float4*)(r1 + 4 * q);
      *(float4*)&P2[4 * q] = *(const float4*)(r2 + 4 * q);
    }
    #pragma unroll
    for (int k = 0; k < 4; ++k) {
      #pragma unroll
      for (int j = k; j < k + 9; ++j) {
        const int xi = j - k;                    // = dxo + 4, compile-time
        const float Fd = fdr[xi];
        const float th = thv[xi];
        float g = Gv[j];
        float tden = fmaf(g, Fd, 1.0f);          // 1 + e^{-8r} e^{8d}
        float w = __builtin_amdgcn_rcpf(tden) * Iv[j];
        w = (g <= th) ? w : 0.0f;                // window mask (r >= m-1)
        wsum[k] += w;
        ac0[k] = fmaf(w, P0[j], ac0[k]);
        ac1[k] = fmaf(w, P1[j], ac1[k]);
        ac2[k] = fmaf(w, P2[j], ac2[k]);
      }
    }
  }

  // Combine the two dy-halves: s=1 publishes partials, s=0 reduces + stores.
  if (s == 1) {
    float4 v0 = {wsum[0], wsum[1], wsum[2], wsum[3]};
    float4 v1 = {ac0[0], ac0[1], ac0[2], ac0[3]};
    float4 v2 = {ac1[0], ac1[1], ac1[2], ac1[3]};
    float4 v3 = {ac2[0], ac2[1], ac2[2], ac2[3]};
    *(float4*)&pbuf[t][0]  = v0;
    *(float4*)&pbuf[t][4]  = v1;
    *(float4*)&pbuf[t][8]  = v2;
    *(float4*)&pbuf[t][12] = v3;
  }
  __syncthreads();
  if (s == 0) {
    float4 v0 = *(const float4*)&pbuf[t][0];
    float4 v1 = *(const float4*)&pbuf[t][4];
    float4 v2 = *(const float4*)&pbuf[t][8];
    float4 v3 = *(const float4*)&pbuf[t][12];
    wsum[0] += v0.x; wsum[1] += v0.y; wsum[2] += v0.z; wsum[3] += v0.w;
    ac0[0] += v1.x; ac0[1] += v1.y; ac0[2] += v1.z; ac0[3] += v1.w;
    ac1[0] += v2.x; ac1[1] += v2.y; ac1[2] += v2.z; ac1[3] += v2.w;
    ac2[0] += v3.x; ac2[1] += v3.y; ac2[2] += v3.z; ac2[3] += v3.w;

    const int oy = by + ty;
    const int ox = bx + col0;
    float rw[4];
    #pragma unroll
    for (int k = 0; k < 4; ++k) rw[k] = __builtin_amdgcn_rcpf(wsum[k]);

    float* op0 = out + ((b * 3 + 0) * HH + oy) * WW + ox;
    float* op1 = out + ((b * 3 + 1) * HH + oy) * WW + ox;
    float* op2 = out + ((b * 3 + 2) * HH + oy) * WW + ox;
    float4 o0, o1, o2;
    o0.x = ac0[0] * rw[0]; o0.y = ac0[1] * rw[1]; o0.z = ac0[2] * rw[2]; o0.w = ac0[3] * rw[3];
    o1.x = ac1[0] * rw[0]; o1.y = ac1[1] * rw[1]; o1.z = ac1[2] * rw[2]; o1.w = ac1[3] * rw[3];
    o2.x = ac2[0] * rw[0]; o2.y = ac2[1] * rw[1]; o2.z = ac2[2] * rw[2]; o2.w = ac2[3] * rw[3];
    *(float4*)op0 = o0;
    *(float4*)op1 = o1;
    *(float4*)op2 = o2;
  }
}

extern "C" void kernel_launch(void* const* d_in, const int* in_sizes, int n_in,
                              void* d_out, int out_size, void* d_ws, size_t ws_size,
                              hipStream_t stream) {
  const float* img = (const float*)d_in[0];   // (2,3,512,512) f32
  const float* def = (const float*)d_in[1];   // (2,1,512,512) f32
  float* out = (float*)d_out;                 // (2,3,512,512) f32

  dim3 grid(WW / TILE, HH / TILE, NB);
  dim3 block(512);
  hipLaunchKernelGGL(bokeh_gather, grid, block, 0, stream, img, def, out);
}